// Round 4
// baseline (10870.565 us; speedup 1.0000x reference)
//
#include <hip/hip_runtime.h>
#include <hip/hip_bf16.h>

// ---------------------------------------------------------------------------
// BottleneckVQa. Encoder fp32 (argmin stability; summation order preserved),
// tiled-LDS direct conv for conv1/conv2; VQ; MFMA bf16 decoder (m97-style
// implicit GEMM for dec2/dec3).
// ---------------------------------------------------------------------------

#define DEV_INLINE __device__ __forceinline__

typedef __attribute__((ext_vector_type(8))) short bf16x8;
typedef __attribute__((ext_vector_type(4))) float f32x4;

#define GLL16(g, l) __builtin_amdgcn_global_load_lds(                      \
    (const __attribute__((address_space(1))) void*)(g),                    \
    (__attribute__((address_space(3))) void*)(l), 16, 0, 0)

DEV_INLINE float gelu_exact(float v) {
    return 0.5f * v * (1.0f + erff(v * 0.70710678118654752440f));
}

// ---- weight transpose to [c][tap][oc] fp32 (oc=64) ----
__global__ void wtf_k(const float* __restrict__ w, float* __restrict__ wt,
                      int C, int total) {
    int t = blockIdx.x * 256 + threadIdx.x;
    if (t >= total) return;
    int oc = t & 63;
    int rest = t >> 6;
    int tap = rest % 25, c = rest / 25;
    wt[t] = w[(oc * C + c) * 25 + tap];
}

// ---- conv1 tiled: [32,3,256,256] -> [32,64,128,128], k5 s2 p2, + gelu ----
// block: 16x16 out tile x 64 oc; thread: 2x2 pos x 16 oc.
__global__ __launch_bounds__(256) void conv1_t(
    const float* __restrict__ x,
    const float* __restrict__ wt,   // [3][25][64]
    float* __restrict__ z1) {
    __shared__ float xin[3 * 1260];   // 3 x [35][36]
    __shared__ float wl[4800];        // [c][tap][oc]
    const int tid = threadIdx.x;
    const int n = blockIdx.z;
    const int OY0 = blockIdx.y * 16, OX0 = blockIdx.x * 16;
    const int IY0 = OY0 * 2 - 2, IX0 = OX0 * 2 - 2;
    const int og = tid & 3;
    const int pg = tid >> 2;
    const int py = (pg >> 3) * 2, px = (pg & 7) * 2;

    // stage weights (once)
    {
        const float4* wsrc = (const float4*)wt;
        float4* wdst = (float4*)wl;
        for (int i = tid; i < 1200; i += 256) wdst[i] = wsrc[i];
    }
    // stage input (once): 3 channels x 35x35
    const float* xn = x + (size_t)n * 3 * 65536;
    for (int i = tid; i < 3675; i += 256) {
        int c = i / 1225, rem = i - c * 1225;
        int r = rem / 35, cl = rem - r * 35;
        int iy = IY0 + r, ix = IX0 + cl;
        float v = 0.f;
        if ((unsigned)iy < 256u && (unsigned)ix < 256u) v = xn[c * 65536 + iy * 256 + ix];
        xin[c * 1260 + r * 36 + cl] = v;
    }
    __syncthreads();

    float acc[4][16] = {};
#pragma unroll
    for (int c = 0; c < 3; ++c) {
        const float* xb = xin + c * 1260 + py * 2 * 36 + px * 2;
#pragma unroll
        for (int ky = 0; ky < 5; ++ky) {
            const float* rA = xb + ky * 36;
            float4 ra0 = *(const float4*)rA;
            float4 ra1 = *(const float4*)(rA + 4);
            float4 rb0 = *(const float4*)(rA + 72);
            float4 rb1 = *(const float4*)(rA + 76);
            float rowA[8] = {ra0.x, ra0.y, ra0.z, ra0.w, ra1.x, ra1.y, ra1.z, ra1.w};
            float rowB[8] = {rb0.x, rb0.y, rb0.z, rb0.w, rb1.x, rb1.y, rb1.z, rb1.w};
#pragma unroll
            for (int kx = 0; kx < 5; ++kx) {
                const float4* wq = (const float4*)wl + ((c * 25 + ky * 5 + kx) << 4) + (og << 2);
                float4 w0 = wq[0], w1 = wq[1], w2 = wq[2], w3 = wq[3];
                float wv[16] = {w0.x, w0.y, w0.z, w0.w, w1.x, w1.y, w1.z, w1.w,
                                w2.x, w2.y, w2.z, w2.w, w3.x, w3.y, w3.z, w3.w};
                float xs[4] = {rowA[kx], rowA[kx + 2], rowB[kx], rowB[kx + 2]};
#pragma unroll
                for (int p = 0; p < 4; ++p) {
                    float xv = xs[p];
#pragma unroll
                    for (int j = 0; j < 16; ++j) acc[p][j] += xv * wv[j];
                }
            }
        }
    }
    const int ocb = og * 16;
#pragma unroll
    for (int p = 0; p < 4; ++p) {
        int oy = OY0 + py + (p >> 1), ox = OX0 + px + (p & 1);
        float* o = z1 + (((size_t)n * 64 + ocb) * 128 + oy) * 128 + ox;
#pragma unroll
        for (int j = 0; j < 16; ++j) o[j * 16384] = gelu_exact(acc[p][j]);
    }
}

// ---- conv2 tiled: [32,64,128,128] -> [32,64,64,64], k5 s2 p2, + gelu ----
__global__ __launch_bounds__(256) void conv2_t(
    const float* __restrict__ z1,
    const float* __restrict__ wt,   // [64][25][64]
    float* __restrict__ z2) {
    __shared__ float xin[1260];       // [35][36]
    __shared__ float wl[1600];        // [tap][oc]
    const int tid = threadIdx.x;
    const int n = blockIdx.z;
    const int OY0 = blockIdx.y * 16, OX0 = blockIdx.x * 16;
    const int IY0 = OY0 * 2 - 2, IX0 = OX0 * 2 - 2;
    const int og = tid & 3;
    const int pg = tid >> 2;
    const int py = (pg >> 3) * 2, px = (pg & 7) * 2;

    float acc[4][16] = {};
    const float* zn = z1 + (size_t)n * 64 * 16384;

    for (int c = 0; c < 64; ++c) {
        // stage weights for channel c (1600 f contiguous)
        {
            const float4* wsrc = (const float4*)(wt + c * 1600);
            float4* wdst = (float4*)wl;
            wdst[tid] = wsrc[tid];
            if (tid < 144) wdst[256 + tid] = wsrc[256 + tid];
        }
        // stage input tile 35x35
        const float* zc = zn + c * 16384;
        for (int i = tid; i < 1225; i += 256) {
            int r = i / 35, cl = i - r * 35;
            int iy = IY0 + r, ix = IX0 + cl;
            float v = 0.f;
            if ((unsigned)iy < 128u && (unsigned)ix < 128u) v = zc[iy * 128 + ix];
            xin[r * 36 + cl] = v;
        }
        __syncthreads();
        const float* xb = xin + py * 2 * 36 + px * 2;
#pragma unroll
        for (int ky = 0; ky < 5; ++ky) {
            const float* rA = xb + ky * 36;
            float4 ra0 = *(const float4*)rA;
            float4 ra1 = *(const float4*)(rA + 4);
            float4 rb0 = *(const float4*)(rA + 72);
            float4 rb1 = *(const float4*)(rA + 76);
            float rowA[8] = {ra0.x, ra0.y, ra0.z, ra0.w, ra1.x, ra1.y, ra1.z, ra1.w};
            float rowB[8] = {rb0.x, rb0.y, rb0.z, rb0.w, rb1.x, rb1.y, rb1.z, rb1.w};
#pragma unroll
            for (int kx = 0; kx < 5; ++kx) {
                const float4* wq = (const float4*)wl + ((ky * 5 + kx) << 4) + (og << 2);
                float4 w0 = wq[0], w1 = wq[1], w2 = wq[2], w3 = wq[3];
                float wv[16] = {w0.x, w0.y, w0.z, w0.w, w1.x, w1.y, w1.z, w1.w,
                                w2.x, w2.y, w2.z, w2.w, w3.x, w3.y, w3.z, w3.w};
                float xs[4] = {rowA[kx], rowA[kx + 2], rowB[kx], rowB[kx + 2]};
#pragma unroll
                for (int p = 0; p < 4; ++p) {
                    float xv = xs[p];
#pragma unroll
                    for (int j = 0; j < 16; ++j) acc[p][j] += xv * wv[j];
                }
            }
        }
        __syncthreads();
    }
    const int ocb = og * 16;
#pragma unroll
    for (int p = 0; p < 4; ++p) {
        int oy = OY0 + py + (p >> 1), ox = OX0 + px + (p & 1);
        float* o = z2 + (((size_t)n * 64 + ocb) * 64 + oy) * 64 + ox;
#pragma unroll
        for (int j = 0; j < 16; ++j) o[j * 4096] = gelu_exact(acc[p][j]);
    }
}

// ---- conv3: [32,64,64,64] -> [32,64,63,63], k2 s1 p0, fp32 ----
__global__ void conv3_k(const float* __restrict__ z2,
                        const float* __restrict__ w,   // [64,64,2,2]
                        float* __restrict__ z) {
    __shared__ float wl[1024];
    const int oc0 = blockIdx.y * 4;
    for (int i = threadIdx.x; i < 1024; i += 256) {
        int j = i & 3, r = i >> 2;
        wl[i] = w[(oc0 + j) * 256 + r];
    }
    __syncthreads();
    const int s = blockIdx.x * 256 + threadIdx.x;
    if (s >= 3969) return;
    const int n = blockIdx.z;
    const int oy = s / 63, ox = s % 63;
    const float4* wv = (const float4*)wl;
    float a0 = 0.f, a1 = 0.f, a2 = 0.f, a3 = 0.f;
    const float* zn = z2 + n * 64 * 4096;
    for (int c = 0; c < 64; ++c) {
        const float* zc = zn + c * 4096;
#pragma unroll
        for (int tap = 0; tap < 4; ++tap) {
            int iy = oy + (tap >> 1), ix = ox + (tap & 1);
            float xv = zc[iy * 64 + ix];
            float4 wq = wv[c * 4 + tap];
            a0 += xv * wq.x; a1 += xv * wq.y; a2 += xv * wq.z; a3 += xv * wq.w;
        }
    }
    int obase = (n * 64 + oc0) * 3969 + s;
    z[obase]            = a0;
    z[obase + 3969]     = a1;
    z[obase + 2 * 3969] = a2;
    z[obase + 3 * 3969] = a3;
}

// ---- VQ: argmin over 24 codes, z_probs (fp32), commitment loss ----
__global__ void vq_k(const float* __restrict__ z,
                     const float* __restrict__ codes,
                     const float* __restrict__ ema,
                     int* __restrict__ idxO,
                     float* __restrict__ zprobsO,
                     float* __restrict__ lossO) {
    __shared__ float cl[1536];
    __shared__ float cn[24];
    __shared__ float pr[24];
    for (int i = threadIdx.x; i < 1536; i += 256) cl[i] = codes[i];
    if (threadIdx.x < 24) pr[threadIdx.x] = ema[threadIdx.x];
    __syncthreads();
    if (threadIdx.x < 24) {
        float sm = 0.f;
        for (int c = 0; c < 64; ++c) { float v = cl[threadIdx.x * 64 + c]; sm += v * v; }
        cn[threadIdx.x] = sm;
    }
    __syncthreads();
    int t = blockIdx.x * 256 + threadIdx.x;
    float l = 0.f;
    if (t < 127008) {
        int b = t / 3969, s = t - b * 3969;
        const float* zp = z + (b * 64) * 3969 + s;
        float zv[64];
        float zn = 0.f;
#pragma unroll
        for (int c = 0; c < 64; ++c) { float v = zp[c * 3969]; zv[c] = v; zn += v * v; }
        float best = 1e30f; int bi = 0;
        for (int k = 0; k < 24; ++k) {
            float dot = 0.f;
#pragma unroll
            for (int c = 0; c < 64; ++c) dot += zv[c] * cl[k * 64 + c];
            float d = zn - 2.f * dot + cn[k];
            if (d < best) { best = d; bi = k; }
        }
        idxO[t] = bi;
        float psum = 0.f;
        for (int k = 0; k < 24; ++k) psum += pr[k];
        zprobsO[t] = pr[bi] / psum;
        for (int c = 0; c < 64; ++c) { float dd = cl[bi * 64 + c] - zv[c]; l += dd * dd; }
    }
    for (int off = 32; off; off >>= 1) l += __shfl_down(l, off, 64);
    if ((threadIdx.x & 63) == 0) atomicAdd(lossO, l);
}

// ---- D table: D[k][tap][oc] = sum_c codes[k][c] * dec_w1[oc][c][tap] ----
__global__ void dtab_k(const float* __restrict__ codes,
                       const float* __restrict__ w1,  // [512,64,2,2]
                       float* __restrict__ D) {
    int t = blockIdx.x * 256 + threadIdx.x;
    if (t >= 24 * 4 * 512) return;
    int oc = t & 511, tap = (t >> 9) & 3, k = t >> 11;
    float acc = 0.f;
    for (int c = 0; c < 64; ++c)
        acc += codes[k * 64 + c] * w1[oc * 256 + c * 4 + tap];
    D[t] = acc;
}

// ---- weight transform: wT[oc][tap][c] bf16 from w[oc][c][2][2] fp32 ----
__global__ void wt_k(const float* __restrict__ w, __hip_bfloat16* __restrict__ wT,
                     int cl2, int total) {
    int t = blockIdx.x * 256 + threadIdx.x;
    if (t >= total) return;
    int c = t & ((1 << cl2) - 1);
    int tap = (t >> cl2) & 3;
    int oc = t >> (cl2 + 2);
    wT[t] = __float2bfloat16(w[((oc << cl2) + c) * 4 + tap]);
}

// ---- dec1: codebook gather -> y1 NHWC [32][64][64][512] bf16, + gelu ----
__global__ void dec1_k(const int* __restrict__ idx,   // [32,63,63]
                       const float* __restrict__ D,   // [24][4][512]
                       __hip_bfloat16* __restrict__ y1) {
    const int pos = blockIdx.x;
    const int n = pos >> 12, rem = pos & 4095;
    const int iy = rem >> 6, ix = rem & 63;
    const int* idn = idx + n * 3969;
    const int t = threadIdx.x;
    float ax = 0.f, ay = 0.f;
#pragma unroll
    for (int tap = 0; tap < 4; ++tap) {
        int py = iy - 1 + (tap >> 1), px = ix - 1 + (tap & 1);
        if ((unsigned)py < 63u && (unsigned)px < 63u) {
            int k = idn[py * 63 + px];
            float2 v = ((const float2*)(D + (k * 4 + tap) * 512))[t];
            ax += v.x; ay += v.y;
        }
    }
    __hip_bfloat162 o;
    o.x = __float2bfloat16(gelu_exact(ax));
    o.y = __float2bfloat16(gelu_exact(ay));
    ((__hip_bfloat162*)(y1 + (size_t)pos * 512))[t] = o;
}

// ---- dec2 MFMA: C[pos][oc] = sum_k y1im2col[pos][k] * wT2[oc][k] ----
__global__ __launch_bounds__(256) void dec2_mfma(
    const __hip_bfloat16* __restrict__ y1,   // NHWC [32][64][64][512]
    const __hip_bfloat16* __restrict__ wT,   // [256][2048]
    const __hip_bfloat16* __restrict__ zp,   // zero page
    __hip_bfloat16* __restrict__ y2)         // NHWC [32][63][63][256]
{
    __shared__ __hip_bfloat16 As[128 * 32];
    __shared__ __hip_bfloat16 Bs[128 * 32];
    const int tid = threadIdx.x;
    const int wave = tid >> 6, lane = tid & 63;
    const int quad = lane >> 4, l15 = lane & 15;
    const int m0 = blockIdx.x * 128;
    const int oc0 = blockIdx.y * 128;
    const int sub = tid & 3;

    const char* pA[2];
    const char* pB[2];
#pragma unroll
    for (int j = 0; j < 2; ++j) {
        int slot = j * 64 + (tid >> 2);
        int pp = m0 + slot;
        if (pp < 127008) {
            int n = pp / 3969; int r = pp - n * 3969;
            int oy = r / 63;  int ox = r - oy * 63;
            pA[j] = (const char*)y1 + (size_t)((n * 64 + oy) * 64 + ox) * 1024 + sub * 16;
        } else {
            pA[j] = (const char*)zp;
        }
        pB[j] = (const char*)wT + (size_t)(oc0 + slot) * 4096 + sub * 16;
    }
    char* ldsA[2] = {(char*)As + wave * 1024, (char*)As + 4096 + wave * 1024};
    char* ldsB[2] = {(char*)Bs + wave * 1024, (char*)Bs + 4096 + wave * 1024};

    f32x4 acc[4][4] = {};
    const int wm = (wave & 1) * 64;
    const int wn = (wave >> 1) * 64;

#pragma unroll
    for (int tap = 0; tap < 4; ++tap) {
        const int toff = ((tap >> 1) * 64 + (tap & 1)) * 1024;
        for (int kk = 0; kk < 16; ++kk) {
            const int cb = kk * 64;
            GLL16(pA[0] + toff + cb, ldsA[0]);
            GLL16(pA[1] + toff + cb, ldsA[1]);
            GLL16(pB[0] + tap * 1024 + cb, ldsB[0]);
            GLL16(pB[1] + tap * 1024 + cb, ldsB[1]);
            __syncthreads();
            bf16x8 af[4], bf[4];
#pragma unroll
            for (int mi = 0; mi < 4; ++mi)
                af[mi] = *(const bf16x8*)((const char*)As + (wm + mi * 16 + l15) * 64 + quad * 16);
#pragma unroll
            for (int ni = 0; ni < 4; ++ni)
                bf[ni] = *(const bf16x8*)((const char*)Bs + (wn + ni * 16 + l15) * 64 + quad * 16);
#pragma unroll
            for (int mi = 0; mi < 4; ++mi)
#pragma unroll
                for (int ni = 0; ni < 4; ++ni)
                    acc[mi][ni] = __builtin_amdgcn_mfma_f32_16x16x32_bf16(
                        af[mi], bf[ni], acc[mi][ni], 0, 0, 0);
            __syncthreads();
        }
    }
#pragma unroll
    for (int mi = 0; mi < 4; ++mi)
#pragma unroll
        for (int r = 0; r < 4; ++r) {
            int pos = m0 + wm + mi * 16 + quad * 4 + r;
            if (pos < 127008) {
#pragma unroll
                for (int ni = 0; ni < 4; ++ni) {
                    int oc = oc0 + wn + ni * 16 + l15;
                    y2[(size_t)pos * 256 + oc] =
                        __float2bfloat16(gelu_exact(acc[mi][ni][r]));
                }
            }
        }
}

// ---- dec3 MFMA: C[oc][pos] = sum_k wT3[oc][k] * y2im2col[pos][k] ----
__global__ __launch_bounds__(256) void dec3_mfma(
    const __hip_bfloat16* __restrict__ y2,   // NHWC [32][63][63][256]
    const __hip_bfloat16* __restrict__ wT,   // [256][1024]
    const __hip_bfloat16* __restrict__ zp,
    float* __restrict__ out)                 // NCHW [32][256][64][64]
{
    __shared__ __hip_bfloat16 As[128 * 32];
    __shared__ __hip_bfloat16 Bs[128 * 32];
    const int tid = threadIdx.x;
    const int wave = tid >> 6, lane = tid & 63;
    const int quad = lane >> 4, l15 = lane & 15;
    const int p0 = blockIdx.x * 128;
    const int oc0 = blockIdx.y * 128;
    const int sub = tid & 3;

    const char* pW[2];
    const char* pP[4][2];
#pragma unroll
    for (int j = 0; j < 2; ++j) {
        int slot = j * 64 + (tid >> 2);
        pW[j] = (const char*)wT + (size_t)(oc0 + slot) * 2048 + sub * 16;
        int pp = p0 + slot;
        int n = pp >> 12, rem = pp & 4095;
        int OY = rem >> 6, OX = rem & 63;
#pragma unroll
        for (int tap = 0; tap < 4; ++tap) {
            int iy = OY - 1 + (tap >> 1), ix = OX - 1 + (tap & 1);
            if ((unsigned)iy < 63u && (unsigned)ix < 63u)
                pP[tap][j] = (const char*)y2 + (size_t)(n * 3969 + iy * 63 + ix) * 512 + sub * 16;
            else
                pP[tap][j] = (const char*)zp;
        }
    }
    char* ldsA[2] = {(char*)As + wave * 1024, (char*)As + 4096 + wave * 1024};
    char* ldsB[2] = {(char*)Bs + wave * 1024, (char*)Bs + 4096 + wave * 1024};

    f32x4 acc[4][4] = {};
    const int wm = (wave & 1) * 64;
    const int wn = (wave >> 1) * 64;

#pragma unroll
    for (int tap = 0; tap < 4; ++tap) {
        for (int kk = 0; kk < 8; ++kk) {
            const int cb = kk * 64;
            GLL16(pW[0] + tap * 512 + cb, ldsA[0]);
            GLL16(pW[1] + tap * 512 + cb, ldsA[1]);
            GLL16(pP[tap][0] + cb, ldsB[0]);
            GLL16(pP[tap][1] + cb, ldsB[1]);
            __syncthreads();
            bf16x8 af[4], bf[4];
#pragma unroll
            for (int mi = 0; mi < 4; ++mi)
                af[mi] = *(const bf16x8*)((const char*)As + (wm + mi * 16 + l15) * 64 + quad * 16);
#pragma unroll
            for (int ni = 0; ni < 4; ++ni)
                bf[ni] = *(const bf16x8*)((const char*)Bs + (wn + ni * 16 + l15) * 64 + quad * 16);
#pragma unroll
            for (int mi = 0; mi < 4; ++mi)
#pragma unroll
                for (int ni = 0; ni < 4; ++ni)
                    acc[mi][ni] = __builtin_amdgcn_mfma_f32_16x16x32_bf16(
                        af[mi], bf[ni], acc[mi][ni], 0, 0, 0);
            __syncthreads();
        }
    }
    const int n = p0 >> 12;
    const int posLocal0 = (p0 & 4095) + wn;
#pragma unroll
    for (int mi = 0; mi < 4; ++mi)
#pragma unroll
        for (int r = 0; r < 4; ++r) {
            int oc = oc0 + wm + mi * 16 + quad * 4 + r;
            float* orow = out + ((size_t)(n * 256 + oc) << 12);
#pragma unroll
            for (int ni = 0; ni < 4; ++ni)
                orow[posLocal0 + ni * 16 + l15] = acc[mi][ni][r];
        }
}

// ---- scalar: vq_loss = 0.25 * sum / (B*C*H*W) ----
__global__ void loss_k(const float* __restrict__ lossO, float* __restrict__ out) {
    out[0] = 0.25f * lossO[0] / 8128512.0f;
}

extern "C" void kernel_launch(void* const* d_in, const int* in_sizes, int n_in,
                              void* d_out, int out_size, void* d_ws, size_t ws_size,
                              hipStream_t stream) {
    const float* x     = (const float*)d_in[0];
    const float* ew1   = (const float*)d_in[1];
    const float* ew2   = (const float*)d_in[2];
    const float* ew3   = (const float*)d_in[3];
    const float* dw1   = (const float*)d_in[4];
    const float* dw2   = (const float*)d_in[5];
    const float* dw3   = (const float*)d_in[6];
    const float* codes = (const float*)d_in[7];
    const float* ema   = (const float*)d_in[8];
    float* out = (float*)d_out;

    char* ws = (char*)d_ws;
    float* z1   = (float*)(ws + 0);            // [32,64,128,128] f32
    float* z2   = (float*)(ws + 134217728);    // [32,64,64,64]  f32
    float* z    = (float*)(ws + 167772160);    // [32,64,63,63]  f32
    int*   idx  = (int*)  (ws + 200286208);    // [32,63,63]     i32
    float* loss = (float*)(ws + 200794240);    // accumulator
    __hip_bfloat16* zp  = (__hip_bfloat16*)(ws + 200794496);  // 69,632 B zero page
    float* D    = (float*)(ws + 200864128);    // [24,4,512] f32
    __hip_bfloat16* wT2 = (__hip_bfloat16*)(ws + 201650560);  // 1 MB [256][2048]
    __hip_bfloat16* wT3 = (__hip_bfloat16*)(ws + 202699136);  // 512 KB [256][1024]
    // encoder-phase scratch overlapping decoder weight regions (dead until wt_k):
    float* wt2f = (float*)(ws + 201650560);    // 409,600 B [64][25][64] (= wT2 region)
    float* wt1f = (float*)(ws + 202699136);    //  19,200 B [3][25][64]  (= wT3 region)
    __hip_bfloat16* y1  = (__hip_bfloat16*)(ws + 0);          // reuse z1
    __hip_bfloat16* y2  = (__hip_bfloat16*)(ws + 134217728);  // reuse z2+z

    hipMemsetAsync(loss, 0, 4, stream);
    hipMemsetAsync(zp, 0, 69632, stream);

    wtf_k<<<dim3(19), 256, 0, stream>>>(ew1, wt1f, 3, 4800);
    wtf_k<<<dim3(400), 256, 0, stream>>>(ew2, wt2f, 64, 102400);
    conv1_t<<<dim3(8, 8, 32), 256, 0, stream>>>(x, wt1f, z1);
    conv2_t<<<dim3(4, 4, 32), 256, 0, stream>>>(z1, wt2f, z2);
    conv3_k<<<dim3(16, 16, 32), 256, 0, stream>>>(z2, ew3, z);
    vq_k<<<dim3(497), 256, 0, stream>>>(z, codes, ema, idx, out + 33554432, loss);
    dtab_k<<<dim3(192), 256, 0, stream>>>(codes, dw1, D);
    wt_k<<<dim3(2048), 256, 0, stream>>>(dw2, wT2, 9, 524288);   // overwrites wt2f (dead)
    wt_k<<<dim3(1024), 256, 0, stream>>>(dw3, wT3, 8, 262144);   // overwrites wt1f (dead)
    dec1_k<<<dim3(131072), 256, 0, stream>>>(idx, D, y1);
    dec2_mfma<<<dim3(993, 2), 256, 0, stream>>>(y1, wT2, zp, y2);
    dec3_mfma<<<dim3(1024, 2), 256, 0, stream>>>(y2, wT3, zp, out);
    loss_k<<<1, 1, 0, stream>>>(loss, out + 33681440);
}

// Round 5
// 1227.578 us; speedup vs baseline: 8.8553x; 8.8553x over previous
//
#include <hip/hip_runtime.h>
#include <hip/hip_bf16.h>

// ---------------------------------------------------------------------------
// BottleneckVQa. Encoder fp32 (argmin stability; summation order preserved),
// tiled-LDS direct conv for conv1/conv2 (named f32x4 accumulators, no
// dynamically-indexed arrays -> no scratch spill); VQ; MFMA bf16 decoder.
// ---------------------------------------------------------------------------

#define DEV_INLINE __device__ __forceinline__

typedef __attribute__((ext_vector_type(8))) short bf16x8;
typedef __attribute__((ext_vector_type(4))) float f32x4;

#define GLL16(g, l) __builtin_amdgcn_global_load_lds(                      \
    (const __attribute__((address_space(1))) void*)(g),                    \
    (__attribute__((address_space(3))) void*)(l), 16, 0, 0)

DEV_INLINE float gelu_exact(float v) {
    return 0.5f * v * (1.0f + erff(v * 0.70710678118654752440f));
}

// ---- weight transpose to [c][tap][oc] fp32 (oc=64) ----
__global__ void wtf_k(const float* __restrict__ w, float* __restrict__ wt,
                      int C, int total) {
    int t = blockIdx.x * 256 + threadIdx.x;
    if (t >= total) return;
    int oc = t & 63;
    int rest = t >> 6;
    int tap = rest % 25, c = rest / 25;
    wt[t] = w[(oc * C + c) * 25 + tap];
}

// ---- conv k5 s2 p2 + gelu, 64 oc, templated on C/IH/IW ----
// block: 16x16 out tile x 64 oc; thread: 2x2 pos x 16 oc (16 named f32x4 acc).
template<int C, int IH, int IW>
__global__ __launch_bounds__(256) void conv5s2_t(
    const float* __restrict__ xg,
    const float* __restrict__ wt,   // [C][25][64]
    float* __restrict__ outg) {     // [32][64][IH/2][IW/2]
    constexpr int OH = IH / 2, OW = IW / 2;
    __shared__ float xin[35 * 36];
    __shared__ float wl[1600];
    const int tid = threadIdx.x;
    const int n = blockIdx.z;
    const int OY0 = blockIdx.y * 16, OX0 = blockIdx.x * 16;
    const int IY0 = OY0 * 2 - 2, IX0 = OX0 * 2 - 2;
    const int og = tid & 3;          // oc group: oc = og*16 + q*4 + {0..3}
    const int pg = tid >> 2;         // 64 position groups (8x8 of 2x2)
    const int py = (pg >> 3) * 2, px = (pg & 7) * 2;
    const int ry = py * 2, rx = px * 2;  // input-local base

    f32x4 a00 = {0,0,0,0}, a01 = a00, a02 = a00, a03 = a00;
    f32x4 a10 = a00, a11 = a00, a12 = a00, a13 = a00;
    f32x4 a20 = a00, a21 = a00, a22 = a00, a23 = a00;
    f32x4 a30 = a00, a31 = a00, a32 = a00, a33 = a00;

    const float* xn = xg + (size_t)n * C * IH * IW;
    for (int c = 0; c < C; ++c) {
        {   // stage weights for channel c: 1600 floats
            const float4* wsrc = (const float4*)(wt + c * 1600);
            float4* wdst = (float4*)wl;
            wdst[tid] = wsrc[tid];
            if (tid < 144) wdst[256 + tid] = wsrc[256 + tid];
        }
        const float* zc = xn + (size_t)c * IH * IW;
        for (int i = tid; i < 1225; i += 256) {
            int r = i / 35, cl = i - r * 35;
            int iy = IY0 + r, ix = IX0 + cl;
            float v = 0.f;
            if ((unsigned)iy < (unsigned)IH && (unsigned)ix < (unsigned)IW)
                v = zc[(size_t)iy * IW + ix];
            xin[r * 36 + cl] = v;
        }
        __syncthreads();
#pragma unroll
        for (int ky = 0; ky < 5; ++ky) {
            const float* r0 = xin + (ry + ky) * 36 + rx;
            const float* r1 = r0 + 72;
#pragma unroll
            for (int kx = 0; kx < 5; ++kx) {
                const f32x4* wq = (const f32x4*)(wl + (ky * 5 + kx) * 64 + og * 16);
                f32x4 w0 = wq[0], w1 = wq[1], w2 = wq[2], w3 = wq[3];
                float xA = r0[kx], xB = r0[kx + 2];
                float xC = r1[kx], xD = r1[kx + 2];
                a00 += xA * w0; a01 += xA * w1; a02 += xA * w2; a03 += xA * w3;
                a10 += xB * w0; a11 += xB * w1; a12 += xB * w2; a13 += xB * w3;
                a20 += xC * w0; a21 += xC * w1; a22 += xC * w2; a23 += xC * w3;
                a30 += xD * w0; a31 += xD * w1; a32 += xD * w2; a33 += xD * w3;
            }
        }
        __syncthreads();
    }
    const int ocb = og * 16;
#define CSTORE(v, oy, ox, q) {                                                \
        float* o = outg + (((size_t)n * 64 + ocb + (q) * 4) * OH + (oy)) * OW \
                   + (ox);                                                    \
        o[0]               = gelu_exact((v).x);                               \
        o[(size_t)OH * OW]     = gelu_exact((v).y);                           \
        o[(size_t)2 * OH * OW] = gelu_exact((v).z);                           \
        o[(size_t)3 * OH * OW] = gelu_exact((v).w); }
    CSTORE(a00, OY0 + py,     OX0 + px,     0); CSTORE(a01, OY0 + py,     OX0 + px,     1);
    CSTORE(a02, OY0 + py,     OX0 + px,     2); CSTORE(a03, OY0 + py,     OX0 + px,     3);
    CSTORE(a10, OY0 + py,     OX0 + px + 1, 0); CSTORE(a11, OY0 + py,     OX0 + px + 1, 1);
    CSTORE(a12, OY0 + py,     OX0 + px + 1, 2); CSTORE(a13, OY0 + py,     OX0 + px + 1, 3);
    CSTORE(a20, OY0 + py + 1, OX0 + px,     0); CSTORE(a21, OY0 + py + 1, OX0 + px,     1);
    CSTORE(a22, OY0 + py + 1, OX0 + px,     2); CSTORE(a23, OY0 + py + 1, OX0 + px,     3);
    CSTORE(a30, OY0 + py + 1, OX0 + px + 1, 0); CSTORE(a31, OY0 + py + 1, OX0 + px + 1, 1);
    CSTORE(a32, OY0 + py + 1, OX0 + px + 1, 2); CSTORE(a33, OY0 + py + 1, OX0 + px + 1, 3);
#undef CSTORE
}

// ---- conv3: [32,64,64,64] -> [32,64,63,63], k2 s1 p0, fp32 ----
__global__ void conv3_k(const float* __restrict__ z2,
                        const float* __restrict__ w,   // [64,64,2,2]
                        float* __restrict__ z) {
    __shared__ float wl[1024];
    const int oc0 = blockIdx.y * 4;
    for (int i = threadIdx.x; i < 1024; i += 256) {
        int j = i & 3, r = i >> 2;
        wl[i] = w[(oc0 + j) * 256 + r];
    }
    __syncthreads();
    const int s = blockIdx.x * 256 + threadIdx.x;
    if (s >= 3969) return;
    const int n = blockIdx.z;
    const int oy = s / 63, ox = s % 63;
    const float4* wv = (const float4*)wl;
    float a0 = 0.f, a1 = 0.f, a2 = 0.f, a3 = 0.f;
    const float* zn = z2 + n * 64 * 4096;
    for (int c = 0; c < 64; ++c) {
        const float* zc = zn + c * 4096;
#pragma unroll
        for (int tap = 0; tap < 4; ++tap) {
            int iy = oy + (tap >> 1), ix = ox + (tap & 1);
            float xv = zc[iy * 64 + ix];
            float4 wq = wv[c * 4 + tap];
            a0 += xv * wq.x; a1 += xv * wq.y; a2 += xv * wq.z; a3 += xv * wq.w;
        }
    }
    int obase = (n * 64 + oc0) * 3969 + s;
    z[obase]            = a0;
    z[obase + 3969]     = a1;
    z[obase + 2 * 3969] = a2;
    z[obase + 3 * 3969] = a3;
}

// ---- VQ: argmin over 24 codes, z_probs (fp32), commitment loss ----
__global__ void vq_k(const float* __restrict__ z,
                     const float* __restrict__ codes,
                     const float* __restrict__ ema,
                     int* __restrict__ idxO,
                     float* __restrict__ zprobsO,
                     float* __restrict__ lossO) {
    __shared__ float cl[1536];
    __shared__ float cn[24];
    __shared__ float pr[24];
    for (int i = threadIdx.x; i < 1536; i += 256) cl[i] = codes[i];
    if (threadIdx.x < 24) pr[threadIdx.x] = ema[threadIdx.x];
    __syncthreads();
    if (threadIdx.x < 24) {
        float sm = 0.f;
        for (int c = 0; c < 64; ++c) { float v = cl[threadIdx.x * 64 + c]; sm += v * v; }
        cn[threadIdx.x] = sm;
    }
    __syncthreads();
    int t = blockIdx.x * 256 + threadIdx.x;
    float l = 0.f;
    if (t < 127008) {
        int b = t / 3969, s = t - b * 3969;
        const float* zp = z + (b * 64) * 3969 + s;
        float zv[64];
        float zn = 0.f;
#pragma unroll
        for (int c = 0; c < 64; ++c) { float v = zp[c * 3969]; zv[c] = v; zn += v * v; }
        float best = 1e30f; int bi = 0;
        for (int k = 0; k < 24; ++k) {
            float dot = 0.f;
#pragma unroll
            for (int c = 0; c < 64; ++c) dot += zv[c] * cl[k * 64 + c];
            float d = zn - 2.f * dot + cn[k];
            if (d < best) { best = d; bi = k; }
        }
        idxO[t] = bi;
        float psum = 0.f;
        for (int k = 0; k < 24; ++k) psum += pr[k];
        zprobsO[t] = pr[bi] / psum;
        for (int c = 0; c < 64; ++c) { float dd = cl[bi * 64 + c] - zv[c]; l += dd * dd; }
    }
    for (int off = 32; off; off >>= 1) l += __shfl_down(l, off, 64);
    if ((threadIdx.x & 63) == 0) atomicAdd(lossO, l);
}

// ---- D table: D[k][tap][oc] = sum_c codes[k][c] * dec_w1[oc][c][tap] ----
__global__ void dtab_k(const float* __restrict__ codes,
                       const float* __restrict__ w1,  // [512,64,2,2]
                       float* __restrict__ D) {
    int t = blockIdx.x * 256 + threadIdx.x;
    if (t >= 24 * 4 * 512) return;
    int oc = t & 511, tap = (t >> 9) & 3, k = t >> 11;
    float acc = 0.f;
    for (int c = 0; c < 64; ++c)
        acc += codes[k * 64 + c] * w1[oc * 256 + c * 4 + tap];
    D[t] = acc;
}

// ---- weight transform: wT[oc][tap][c] bf16 from w[oc][c][2][2] fp32 ----
__global__ void wt_k(const float* __restrict__ w, __hip_bfloat16* __restrict__ wT,
                     int cl2, int total) {
    int t = blockIdx.x * 256 + threadIdx.x;
    if (t >= total) return;
    int c = t & ((1 << cl2) - 1);
    int tap = (t >> cl2) & 3;
    int oc = t >> (cl2 + 2);
    wT[t] = __float2bfloat16(w[((oc << cl2) + c) * 4 + tap]);
}

// ---- dec1: codebook gather -> y1 NHWC [32][64][64][512] bf16, + gelu ----
__global__ void dec1_k(const int* __restrict__ idx,   // [32,63,63]
                       const float* __restrict__ D,   // [24][4][512]
                       __hip_bfloat16* __restrict__ y1) {
    const int pos = blockIdx.x;
    const int n = pos >> 12, rem = pos & 4095;
    const int iy = rem >> 6, ix = rem & 63;
    const int* idn = idx + n * 3969;
    const int t = threadIdx.x;
    float ax = 0.f, ay = 0.f;
#pragma unroll
    for (int tap = 0; tap < 4; ++tap) {
        int py = iy - 1 + (tap >> 1), px = ix - 1 + (tap & 1);
        if ((unsigned)py < 63u && (unsigned)px < 63u) {
            int k = idn[py * 63 + px];
            float2 v = ((const float2*)(D + (k * 4 + tap) * 512))[t];
            ax += v.x; ay += v.y;
        }
    }
    __hip_bfloat162 o;
    o.x = __float2bfloat16(gelu_exact(ax));
    o.y = __float2bfloat16(gelu_exact(ay));
    ((__hip_bfloat162*)(y1 + (size_t)pos * 512))[t] = o;
}

// ---- dec2 MFMA: C[pos][oc] = sum_k y1im2col[pos][k] * wT2[oc][k] ----
__global__ __launch_bounds__(256) void dec2_mfma(
    const __hip_bfloat16* __restrict__ y1,   // NHWC [32][64][64][512]
    const __hip_bfloat16* __restrict__ wT,   // [256][2048]
    const __hip_bfloat16* __restrict__ zp,   // zero page
    __hip_bfloat16* __restrict__ y2)         // NHWC [32][63][63][256]
{
    __shared__ __hip_bfloat16 As[128 * 32];
    __shared__ __hip_bfloat16 Bs[128 * 32];
    const int tid = threadIdx.x;
    const int wave = tid >> 6, lane = tid & 63;
    const int quad = lane >> 4, l15 = lane & 15;
    const int m0 = blockIdx.x * 128;
    const int oc0 = blockIdx.y * 128;
    const int sub = tid & 3;

    const char* pA[2];
    const char* pB[2];
#pragma unroll
    for (int j = 0; j < 2; ++j) {
        int slot = j * 64 + (tid >> 2);
        int pp = m0 + slot;
        if (pp < 127008) {
            int n = pp / 3969; int r = pp - n * 3969;
            int oy = r / 63;  int ox = r - oy * 63;
            pA[j] = (const char*)y1 + (size_t)((n * 64 + oy) * 64 + ox) * 1024 + sub * 16;
        } else {
            pA[j] = (const char*)zp;
        }
        pB[j] = (const char*)wT + (size_t)(oc0 + slot) * 4096 + sub * 16;
    }
    char* ldsA[2] = {(char*)As + wave * 1024, (char*)As + 4096 + wave * 1024};
    char* ldsB[2] = {(char*)Bs + wave * 1024, (char*)Bs + 4096 + wave * 1024};

    f32x4 acc[4][4] = {};
    const int wm = (wave & 1) * 64;
    const int wn = (wave >> 1) * 64;

#pragma unroll
    for (int tap = 0; tap < 4; ++tap) {
        const int toff = ((tap >> 1) * 64 + (tap & 1)) * 1024;
        for (int kk = 0; kk < 16; ++kk) {
            const int cb = kk * 64;
            GLL16(pA[0] + toff + cb, ldsA[0]);
            GLL16(pA[1] + toff + cb, ldsA[1]);
            GLL16(pB[0] + tap * 1024 + cb, ldsB[0]);
            GLL16(pB[1] + tap * 1024 + cb, ldsB[1]);
            __syncthreads();
            bf16x8 af[4], bf[4];
#pragma unroll
            for (int mi = 0; mi < 4; ++mi)
                af[mi] = *(const bf16x8*)((const char*)As + (wm + mi * 16 + l15) * 64 + quad * 16);
#pragma unroll
            for (int ni = 0; ni < 4; ++ni)
                bf[ni] = *(const bf16x8*)((const char*)Bs + (wn + ni * 16 + l15) * 64 + quad * 16);
#pragma unroll
            for (int mi = 0; mi < 4; ++mi)
#pragma unroll
                for (int ni = 0; ni < 4; ++ni)
                    acc[mi][ni] = __builtin_amdgcn_mfma_f32_16x16x32_bf16(
                        af[mi], bf[ni], acc[mi][ni], 0, 0, 0);
            __syncthreads();
        }
    }
#pragma unroll
    for (int mi = 0; mi < 4; ++mi)
#pragma unroll
        for (int r = 0; r < 4; ++r) {
            int pos = m0 + wm + mi * 16 + quad * 4 + r;
            if (pos < 127008) {
#pragma unroll
                for (int ni = 0; ni < 4; ++ni) {
                    int oc = oc0 + wn + ni * 16 + l15;
                    y2[(size_t)pos * 256 + oc] =
                        __float2bfloat16(gelu_exact(acc[mi][ni][r]));
                }
            }
        }
}

// ---- dec3 MFMA: C[oc][pos] = sum_k wT3[oc][k] * y2im2col[pos][k] ----
__global__ __launch_bounds__(256) void dec3_mfma(
    const __hip_bfloat16* __restrict__ y2,   // NHWC [32][63][63][256]
    const __hip_bfloat16* __restrict__ wT,   // [256][1024]
    const __hip_bfloat16* __restrict__ zp,
    float* __restrict__ out)                 // NCHW [32][256][64][64]
{
    __shared__ __hip_bfloat16 As[128 * 32];
    __shared__ __hip_bfloat16 Bs[128 * 32];
    const int tid = threadIdx.x;
    const int wave = tid >> 6, lane = tid & 63;
    const int quad = lane >> 4, l15 = lane & 15;
    const int p0 = blockIdx.x * 128;
    const int oc0 = blockIdx.y * 128;
    const int sub = tid & 3;

    const char* pW[2];
    const char* pP[4][2];
#pragma unroll
    for (int j = 0; j < 2; ++j) {
        int slot = j * 64 + (tid >> 2);
        pW[j] = (const char*)wT + (size_t)(oc0 + slot) * 2048 + sub * 16;
        int pp = p0 + slot;
        int n = pp >> 12, rem = pp & 4095;
        int OY = rem >> 6, OX = rem & 63;
#pragma unroll
        for (int tap = 0; tap < 4; ++tap) {
            int iy = OY - 1 + (tap >> 1), ix = OX - 1 + (tap & 1);
            if ((unsigned)iy < 63u && (unsigned)ix < 63u)
                pP[tap][j] = (const char*)y2 + (size_t)(n * 3969 + iy * 63 + ix) * 512 + sub * 16;
            else
                pP[tap][j] = (const char*)zp;
        }
    }
    char* ldsA[2] = {(char*)As + wave * 1024, (char*)As + 4096 + wave * 1024};
    char* ldsB[2] = {(char*)Bs + wave * 1024, (char*)Bs + 4096 + wave * 1024};

    f32x4 acc[4][4] = {};
    const int wm = (wave & 1) * 64;
    const int wn = (wave >> 1) * 64;

#pragma unroll
    for (int tap = 0; tap < 4; ++tap) {
        for (int kk = 0; kk < 8; ++kk) {
            const int cb = kk * 64;
            GLL16(pW[0] + tap * 512 + cb, ldsA[0]);
            GLL16(pW[1] + tap * 512 + cb, ldsA[1]);
            GLL16(pP[tap][0] + cb, ldsB[0]);
            GLL16(pP[tap][1] + cb, ldsB[1]);
            __syncthreads();
            bf16x8 af[4], bf[4];
#pragma unroll
            for (int mi = 0; mi < 4; ++mi)
                af[mi] = *(const bf16x8*)((const char*)As + (wm + mi * 16 + l15) * 64 + quad * 16);
#pragma unroll
            for (int ni = 0; ni < 4; ++ni)
                bf[ni] = *(const bf16x8*)((const char*)Bs + (wn + ni * 16 + l15) * 64 + quad * 16);
#pragma unroll
            for (int mi = 0; mi < 4; ++mi)
#pragma unroll
                for (int ni = 0; ni < 4; ++ni)
                    acc[mi][ni] = __builtin_amdgcn_mfma_f32_16x16x32_bf16(
                        af[mi], bf[ni], acc[mi][ni], 0, 0, 0);
            __syncthreads();
        }
    }
    const int n = p0 >> 12;
    const int posLocal0 = (p0 & 4095) + wn;
#pragma unroll
    for (int mi = 0; mi < 4; ++mi)
#pragma unroll
        for (int r = 0; r < 4; ++r) {
            int oc = oc0 + wm + mi * 16 + quad * 4 + r;
            float* orow = out + ((size_t)(n * 256 + oc) << 12);
#pragma unroll
            for (int ni = 0; ni < 4; ++ni)
                orow[posLocal0 + ni * 16 + l15] = acc[mi][ni][r];
        }
}

// ---- scalar: vq_loss = 0.25 * sum / (B*C*H*W) ----
__global__ void loss_k(const float* __restrict__ lossO, float* __restrict__ out) {
    out[0] = 0.25f * lossO[0] / 8128512.0f;
}

extern "C" void kernel_launch(void* const* d_in, const int* in_sizes, int n_in,
                              void* d_out, int out_size, void* d_ws, size_t ws_size,
                              hipStream_t stream) {
    const float* x     = (const float*)d_in[0];
    const float* ew1   = (const float*)d_in[1];
    const float* ew2   = (const float*)d_in[2];
    const float* ew3   = (const float*)d_in[3];
    const float* dw1   = (const float*)d_in[4];
    const float* dw2   = (const float*)d_in[5];
    const float* dw3   = (const float*)d_in[6];
    const float* codes = (const float*)d_in[7];
    const float* ema   = (const float*)d_in[8];
    float* out = (float*)d_out;

    char* ws = (char*)d_ws;
    float* z1   = (float*)(ws + 0);            // [32,64,128,128] f32
    float* z2   = (float*)(ws + 134217728);    // [32,64,64,64]  f32
    float* z    = (float*)(ws + 167772160);    // [32,64,63,63]  f32
    int*   idx  = (int*)  (ws + 200286208);    // [32,63,63]     i32
    float* loss = (float*)(ws + 200794240);    // accumulator
    __hip_bfloat16* zp  = (__hip_bfloat16*)(ws + 200794496);  // 69,632 B zero page
    float* D    = (float*)(ws + 200864128);    // [24,4,512] f32
    __hip_bfloat16* wT2 = (__hip_bfloat16*)(ws + 201650560);  // 1 MB [256][2048]
    __hip_bfloat16* wT3 = (__hip_bfloat16*)(ws + 202699136);  // 512 KB [256][1024]
    // encoder-phase scratch overlapping decoder weight regions (dead until wt_k):
    float* wt2f = (float*)(ws + 201650560);    // 409,600 B [64][25][64]
    float* wt1f = (float*)(ws + 202699136);    //  19,200 B [3][25][64]
    __hip_bfloat16* y1  = (__hip_bfloat16*)(ws + 0);          // reuse z1
    __hip_bfloat16* y2  = (__hip_bfloat16*)(ws + 134217728);  // reuse z2+z

    hipMemsetAsync(loss, 0, 4, stream);
    hipMemsetAsync(zp, 0, 69632, stream);

    wtf_k<<<dim3(19), 256, 0, stream>>>(ew1, wt1f, 3, 4800);
    wtf_k<<<dim3(400), 256, 0, stream>>>(ew2, wt2f, 64, 102400);
    conv5s2_t<3, 256, 256><<<dim3(8, 8, 32), 256, 0, stream>>>(x, wt1f, z1);
    conv5s2_t<64, 128, 128><<<dim3(4, 4, 32), 256, 0, stream>>>(z1, wt2f, z2);
    conv3_k<<<dim3(16, 16, 32), 256, 0, stream>>>(z2, ew3, z);
    vq_k<<<dim3(497), 256, 0, stream>>>(z, codes, ema, idx, out + 33554432, loss);
    dtab_k<<<dim3(192), 256, 0, stream>>>(codes, dw1, D);
    wt_k<<<dim3(2048), 256, 0, stream>>>(dw2, wT2, 9, 524288);
    wt_k<<<dim3(1024), 256, 0, stream>>>(dw3, wT3, 8, 262144);
    dec1_k<<<dim3(131072), 256, 0, stream>>>(idx, D, y1);
    dec2_mfma<<<dim3(993, 2), 256, 0, stream>>>(y1, wT2, zp, y2);
    dec3_mfma<<<dim3(1024, 2), 256, 0, stream>>>(y2, wT3, zp, out);
    loss_k<<<1, 1, 0, stream>>>(loss, out + 33681440);
}